// Round 4
// baseline (1198.208 us; speedup 1.0000x reference)
//
#include <hip/hip_runtime.h>
#include <hip/hip_bf16.h>

// Encoder: attention-weighted LSTM, B=32768 T=9 D_IN=81 H=128.
// All inputs AND outputs fp32. attn = softmax(pre) is time-invariant
// (logits = pre + scalar broadcast); Wh/Wc dead. Recurrence:
// gates_t = [w_in_t | h_t] @ [W_ih | W_hh]^T + bias.
//
// History:
//  r1 (MFMA rewrite, kNB=32/256th/acc[2][8]): 403us. Latency-bound:
//     VGPR128+AGPR64=192/wave -> 2 waves/SIMD (occ 22%), W refetch 470MB.
//  r3 (kNB=64/512th/acc[4][4], bounds(512,4)): 937us REGRESSION. gfx950
//     unified VGPR/AGPR file: budget 512/4=128 TOTAL; acc took 64 AGPRs,
//     64 arch VGPRs left -> scratch spills (WRITE +630MB, FETCH +300MB).
//  r4 (this): keep 4 waves/SIMD but shrink per-wave tile so state fits 128:
//     kNB=32, 512 threads, 8 waves; wave owns 64 gate-rows x 32 batches
//     (acc[2][4] f32x4 = 32 regs; persistent ~52; total ~100 < 128).
//     1024 blocks at 2/CU -> fully co-resident, 16 waves/CU.
//     Keep: x_{t+1} reg prefetch, NT x loads + NT out stores (protect W
//     in L2; r1 had no NT and refetched W from HBM), bias in pointwise.
// MFMA layout (HW-verified C/D: col=lane&15=batch, row=(lane>>4)*4+reg=p):
// A = W^T tile (M=gate-row p), B = activations^T (N=batch); both operands
// contiguous-8-along-k so internal k-permutation cancels.
// fp32 activation accuracy via bf16 hi+lo planes (2 MFMAs per W fragment).

namespace {

constexpr int kB    = 32768;
constexpr int kT    = 9;
constexpr int kD    = 81;     // D_IN
constexpr int kH    = 128;
constexpr int kG    = 512;    // 4H
constexpr int kK    = 209;    // 81 + 128
constexpr int kKPad = 224;    // padded to 7 MFMA k-steps of 32 (pad rows zeroed)
constexpr int kNB   = 32;     // batch rows per block
constexpr int kTh   = 512;    // threads per block (8 waves)
constexpr int kAS   = 232;    // LDS activation row stride in bf16:
                              // 464B = 29*16 -> rows 16B-aligned; dword stride
                              // 116 == 20 mod 32 -> 2-way bank alias (free)

// ws layout: [Wt bf16 [512][224] gate-permuted rows][bias 512 f32][Wx 16 f32][b_attn f32]
constexpr int kWsWtBytes  = kG * kKPad * 2;      // 229376
constexpr int kWsBiasOff  = kWsWtBytes;
constexpr int kWsWxOff    = kWsBiasOff + kG * 4;
constexpr int kWsBAttnOff = kWsWxOff + 16 * 4;

typedef __bf16 bf16x8 __attribute__((ext_vector_type(8)));
typedef float  f32x4  __attribute__((ext_vector_type(4)));

__device__ __forceinline__ float sigf(float x) {
  return __builtin_amdgcn_rcpf(1.f + __expf(-x));
}
// tanh(x) = 1 - 2/(1+e^{2x}); saturates correctly as exp -> 0/inf
__device__ __forceinline__ float tanhfast(float x) {
  return 1.f - 2.f * __builtin_amdgcn_rcpf(1.f + __expf(2.f * x));
}

// ---- prep: repack weights. Row permutation p = u*4+q (gate g = q*128+u) so
// MFMA D-rows (p) give one lane the {i,f,g,o} quad of unit u. W stored
// TRANSPOSED [p][k] bf16 so A-operand fragments (lane: row=l&15, 8 contiguous
// k) are single 16B loads.
__global__ void prep_kernel(const float* __restrict__ W_attn,
                            const float* __restrict__ b_attn,
                            const float* __restrict__ W_ih,
                            const float* __restrict__ W_hh,
                            const float* __restrict__ b_ih,
                            const float* __restrict__ b_hh,
                            unsigned char* __restrict__ ws) {
  __bf16* Wt   = reinterpret_cast<__bf16*>(ws);
  float* biasp = reinterpret_cast<float*>(ws + kWsBiasOff);
  float* wxp   = reinterpret_cast<float*>(ws + kWsWxOff);
  float* bap   = reinterpret_cast<float*>(ws + kWsBAttnOff);
  int tid = blockIdx.x * blockDim.x + threadIdx.x;
  int nth = gridDim.x * blockDim.x;
  for (int idx = tid; idx < kG * kKPad; idx += nth) {
    int p = idx / kKPad, k = idx - p * kKPad;
    int u = p >> 2, q = p & 3, g = q * kH + u;
    float v = 0.f;
    if (k < kD)      v = W_ih[g * kD + k];
    else if (k < kK) v = W_hh[g * kH + (k - kD)];
    Wt[idx] = (__bf16)v;   // idx == p*kKPad + k
  }
  if (tid < kG) {
    int u = tid >> 2, q = tid & 3, g = q * kH + u;
    biasp[tid] = b_ih[g] + b_hh[g];
  }
  if (tid >= kG && tid < kG + 16) {
    int t = tid - kG;
    wxp[t] = (t < kT) ? W_attn[2 * kH + t] : 0.f;
  }
  if (tid == kG + 16) bap[0] = b_attn[0];
}

__global__ __launch_bounds__(kTh, 4) void enc_main(
    const float* __restrict__ x,              // (B,9,81) fp32
    const unsigned char* __restrict__ ws,
    float* __restrict__ out_w,                // (B,9,81) fp32
    float* __restrict__ out_h) {              // (B,9,128) fp32
  // Activations^T stored as [b][k] row-major bf16, hi and lo planes.
  // k<81: w_in, 81..208: h, 209..231: zero pad.
  __shared__ __align__(16) __bf16 ash[kNB][kAS];
  __shared__ __align__(16) __bf16 asl[kNB][kAS];
  __shared__ __align__(16) float bias_s[kG];
  __shared__ float red[kNB][16];
  __shared__ float wx_s[16];
  __shared__ float battn_s;

  const int tid = threadIdx.x;
  const int b0  = blockIdx.x * kNB;
  const __bf16* Wt = reinterpret_cast<const __bf16*>(ws);

  if (tid < 16) wx_s[tid] = reinterpret_cast<const float*>(ws + kWsWxOff)[tid];
  if (tid == 16) battn_s = reinterpret_cast<const float*>(ws + kWsBAttnOff)[0];
  bias_s[tid] = reinterpret_cast<const float*>(ws + kWsBiasOff)[tid];
  for (int i = tid; i < kNB * kAS; i += kTh) {   // zero (h0=0, k-pad=0)
    (&ash[0][0])[i] = (__bf16)0.f;
    (&asl[0][0])[i] = (__bf16)0.f;
  }
  __syncthreads();

  // ---- pre + softmax once (time-invariant). 16 threads per batch row:
  //      b = tid>>4, d = (tid&15) + 16m, m<6.
  const int sb = tid >> 4;
  const int sq = tid & 15;
  const size_t xbase = (size_t)(b0 + sb) * kT * kD;
  float attn[6];
  {
    float lmax = -3.4e38f;
#pragma unroll
    for (int m = 0; m < 6; ++m) {
      int d = sq + 16 * m;
      float s = -3.4e38f;
      if (d < kD) {
        s = battn_s;
#pragma unroll
        for (int t = 0; t < kT; ++t)
          s += __builtin_nontemporal_load(x + xbase + t * kD + d) * wx_s[t];
        lmax = fmaxf(lmax, s);
      }
      attn[m] = s;
    }
    red[sb][sq] = lmax;
    __syncthreads();
    float gmax = red[sb][0];
#pragma unroll
    for (int r = 1; r < 16; ++r) gmax = fmaxf(gmax, red[sb][r]);
    __syncthreads();
    float lsum = 0.f;
#pragma unroll
    for (int m = 0; m < 6; ++m) {
      float e = __expf(attn[m] - gmax);   // invalid lanes: exp(-huge) = 0
      attn[m] = e;
      lsum += e;
    }
    red[sb][sq] = lsum;
    __syncthreads();
    float tot = 0.f;
#pragma unroll
    for (int r = 0; r < 16; ++r) tot += red[sb][r];
    float inv = 1.0f / tot;
#pragma unroll
    for (int m = 0; m < 6; ++m) attn[m] *= inv;
  }

  // ---- MFMA ids: wave wv owns gate-rows [wv*64,(wv+1)*64) (4 p-tiles),
  //      32 batches (2 batch-tiles of 16).
  const int lane = tid & 63;
  const int wv   = tid >> 6;
  const int lb   = lane & 15;   // A row within p-tile / B col (batch) / D col
  const int kg   = lane >> 4;   // k-group: k = ks*32 + kg*8 + j
  const __bf16* wrow = Wt + (size_t)(wv * 64 + lb) * kKPad;

  float c_reg[2][4];
#pragma unroll
  for (int bt = 0; bt < 2; ++bt)
#pragma unroll
    for (int p = 0; p < 4; ++p) c_reg[bt][p] = 0.f;

  // prologue: prefetch x_0 into registers
  float xr[6];
#pragma unroll
  for (int m = 0; m < 6; ++m) {
    int d = sq + 16 * m;
    xr[m] = (d < kD) ? __builtin_nontemporal_load(x + xbase + d) : 0.f;
  }

  for (int t = 0; t < kT; ++t) {
    // ---- phase A: w_in = attn * x_t (from prefetched regs) -> hi/lo planes
    //      + out_w (fp32 exact); then issue prefetch of x_{t+1}.
    {
      const size_t xoff = xbase + (size_t)t * kD;
#pragma unroll
      for (int m = 0; m < 6; ++m) {
        int d = sq + 16 * m;
        if (d < kD) {
          float w = attn[m] * xr[m];
          __builtin_nontemporal_store(w, out_w + xoff + d);
          __bf16 hi = (__bf16)w;
          ash[sb][d] = hi;
          asl[sb][d] = (__bf16)(w - (float)hi);
        }
      }
      if (t + 1 < kT) {
#pragma unroll
        for (int m = 0; m < 6; ++m) {
          int d = sq + 16 * m;
          if (d < kD)
            xr[m] = __builtin_nontemporal_load(x + xoff + kD + d);
        }
      }
    }
    __syncthreads();   // w_in writes (t) + h writes (t-1) visible to all waves

    // ---- gates = act @ W^T via MFMA (bias added in pointwise)
    f32x4 acc[2][4];
#pragma unroll
    for (int bt = 0; bt < 2; ++bt)
#pragma unroll
      for (int p = 0; p < 4; ++p) acc[bt][p] = (f32x4){0.f, 0.f, 0.f, 0.f};

#pragma unroll
    for (int ks = 0; ks < kKPad / 32; ++ks) {
      const int k0 = ks * 32 + kg * 8;
      bf16x8 wf[4];
#pragma unroll
      for (int p = 0; p < 4; ++p)
        wf[p] = *reinterpret_cast<const bf16x8*>(wrow + p * (16 * kKPad) + k0);
#pragma unroll
      for (int bt = 0; bt < 2; ++bt) {
        bf16x8 bh = *reinterpret_cast<const bf16x8*>(&ash[bt * 16 + lb][k0]);
        bf16x8 bl = *reinterpret_cast<const bf16x8*>(&asl[bt * 16 + lb][k0]);
#pragma unroll
        for (int p = 0; p < 4; ++p) {
          acc[bt][p] = __builtin_amdgcn_mfma_f32_16x16x32_bf16(wf[p], bh, acc[bt][p], 0, 0, 0);
          acc[bt][p] = __builtin_amdgcn_mfma_f32_16x16x32_bf16(wf[p], bl, acc[bt][p], 0, 0, 0);
        }
      }
    }
    __syncthreads();   // all waves' GEMM reads done before h-region rewrite

    // ---- LSTM pointwise: lane holds {i,f,g,o} (= reg 0..3) of (b,u)
    //      b = bt*16 + lb, u = wv*16 + p*4 + kg; c stays in registers.
#pragma unroll
    for (int p = 0; p < 4; ++p) {
      const int u = wv * 16 + p * 4 + kg;
      f32x4 bv = *reinterpret_cast<const f32x4*>(&bias_s[wv * 64 + p * 16 + kg * 4]);
#pragma unroll
      for (int bt = 0; bt < 2; ++bt) {
        f32x4 g4 = acc[bt][p];
        float cn = sigf(g4[1] + bv[1]) * c_reg[bt][p] +
                   sigf(g4[0] + bv[0]) * tanhfast(g4[2] + bv[2]);
        float hn = sigf(g4[3] + bv[3]) * tanhfast(cn);
        c_reg[bt][p] = cn;
        const int b = bt * 16 + lb;
        __builtin_nontemporal_store(
            hn, out_h + ((size_t)(b0 + b) * kT + t) * kH + u);
        __bf16 hi = (__bf16)hn;
        ash[b][kD + u] = hi;                        // k = 81 + u
        asl[b][kD + u] = (__bf16)(hn - (float)hi);
      }
    }
    // no barrier here: next phase A writes k<81 (disjoint from h region);
    // next iteration's barrier orders h writes before GEMM reads.
  }
}

}  // namespace

extern "C" void kernel_launch(void* const* d_in, const int* in_sizes, int n_in,
                              void* d_out, int out_size, void* d_ws, size_t ws_size,
                              hipStream_t stream) {
  (void)in_sizes; (void)n_in; (void)out_size; (void)ws_size;
  const float* x      = (const float*)d_in[0];
  const float* W_attn = (const float*)d_in[1];
  const float* b_attn = (const float*)d_in[2];
  const float* W_ih   = (const float*)d_in[3];
  const float* W_hh   = (const float*)d_in[4];
  const float* b_ih   = (const float*)d_in[5];
  const float* b_hh   = (const float*)d_in[6];
  float* out_w = (float*)d_out;
  float* out_h = out_w + (size_t)kB * kT * kD;
  unsigned char* ws = (unsigned char*)d_ws;

  hipLaunchKernelGGL(prep_kernel, dim3(64), dim3(256), 0, stream,
                     W_attn, b_attn, W_ih, W_hh, b_ih, b_hh, ws);
  hipLaunchKernelGGL(enc_main, dim3(kB / kNB), dim3(kTh), 0, stream,
                     x, ws, out_w, out_h);
}

// Round 5
// 1004.605 us; speedup vs baseline: 1.1927x; 1.1927x over previous
//
#include <hip/hip_runtime.h>
#include <hip/hip_bf16.h>

// Encoder: attention-weighted LSTM, B=32768 T=9 D_IN=81 H=128.
// All inputs AND outputs fp32. attn = softmax(pre) is time-invariant
// (logits = pre + scalar broadcast); Wh/Wc dead. Recurrence:
// gates_t = [w_in_t | h_t] @ [W_ih | W_hh]^T + bias.
//
// History:
//  r1: MFMA rewrite, 256th/4w/kNB=32/acc[2][8], 403us. FETCH 664MB (W
//      refetch 470MB), WRITE 373MB, occ 22%.
//  r3/r4: occupancy chase (512th, bounds(512,4)) REGRESSED to ~940us.
//      Root cause from counters: HBM traffic 2.7GB -- out_h NT scalar
//      stores (4B per 4608B-strided line, no-allocate => no L2 merge,
//      ~8x write amplification) + W refetch ~1GB. NT loads/stores made
//      L2/L3 residency WORSE (r1 no-NT had lowest W miss 22%).
//  r5 (this): r1 skeleton + traffic fixes only:
//      - out_h staged through LDS: pointwise writes h hi/lo to LDS only
//        (already needed for GEMM); after barrier, h = hi+lo reconstructed
//        (err ~4e-6 << 4.9e-4 passing absmax) and stored as contiguous
//        dwordx4 NT (512B/row, zero amplification).
//      - LDS k-layout swapped: h at k=[0,128), w_in at k=[128,209), pad to
//        224 -- h rows 16B-aligned for b128 staged reads. W repacked to match.
//      - x loads plain/cached (r1-style; whole x=95MB fits L3) + x_{t+1}
//        register prefetch.
//      - NT only on full-line output stores (out_w 64B segments, out_h
//        dwordx4): outputs stop thrashing L3, no partial-line writes.
// MFMA layout (HW-verified C/D: col=lane&15=batch, row=(lane>>4)*4+reg=p):
// A = W^T tile (M=gate-row p), B = activations^T (N=batch); both operands
// contiguous-8-along-k so internal k-permutation cancels. Gate-row perm
// p=4u+q => lane's f32x4 acc = {i,f,g,o} of one (b,u): pointwise lane-local.
// fp32 activation accuracy via bf16 hi+lo planes (2 MFMAs per W fragment).

namespace {

constexpr int kB    = 32768;
constexpr int kT    = 9;
constexpr int kD    = 81;     // D_IN
constexpr int kH    = 128;
constexpr int kG    = 512;    // 4H
constexpr int kKPad = 224;    // 7 MFMA k-steps of 32; k<128: h, 128..208: w_in,
                              // 209..223: zero pad
constexpr int kNB   = 32;     // batch rows per block
constexpr int kTh   = 256;    // threads per block (4 waves)
constexpr int kAS   = 232;    // LDS activation row stride in bf16:
                              // 464B = 29*16 -> rows 16B-aligned; dword stride
                              // 116 == 20 mod 32 -> 2-way bank alias (free)

// ws layout: [Wt bf16 [512][224] gate-permuted rows][bias 512 f32][Wx 16 f32][b_attn f32]
constexpr int kWsWtBytes  = kG * kKPad * 2;      // 229376
constexpr int kWsBiasOff  = kWsWtBytes;
constexpr int kWsWxOff    = kWsBiasOff + kG * 4;
constexpr int kWsBAttnOff = kWsWxOff + 16 * 4;

typedef __bf16 bf16x8 __attribute__((ext_vector_type(8)));
typedef float  f32x4  __attribute__((ext_vector_type(4)));

__device__ __forceinline__ float sigf(float x) {
  return __builtin_amdgcn_rcpf(1.f + __expf(-x));
}
// tanh(x) = 1 - 2/(1+e^{2x}); saturates correctly as exp -> 0/inf
__device__ __forceinline__ float tanhfast(float x) {
  return 1.f - 2.f * __builtin_amdgcn_rcpf(1.f + __expf(2.f * x));
}

// ---- prep: repack weights. Gate-row perm p = u*4+q (gate g = q*128+u).
// W stored TRANSPOSED [p][k] bf16, k-layout matching LDS activations:
// k<128 -> W_hh[g][k]; 128<=k<209 -> W_ih[g][k-128]; else 0.
__global__ void prep_kernel(const float* __restrict__ W_attn,
                            const float* __restrict__ b_attn,
                            const float* __restrict__ W_ih,
                            const float* __restrict__ W_hh,
                            const float* __restrict__ b_ih,
                            const float* __restrict__ b_hh,
                            unsigned char* __restrict__ ws) {
  __bf16* Wt   = reinterpret_cast<__bf16*>(ws);
  float* biasp = reinterpret_cast<float*>(ws + kWsBiasOff);
  float* wxp   = reinterpret_cast<float*>(ws + kWsWxOff);
  float* bap   = reinterpret_cast<float*>(ws + kWsBAttnOff);
  int tid = blockIdx.x * blockDim.x + threadIdx.x;
  int nth = gridDim.x * blockDim.x;
  for (int idx = tid; idx < kG * kKPad; idx += nth) {
    int p = idx / kKPad, k = idx - p * kKPad;
    int u = p >> 2, q = p & 3, g = q * kH + u;
    float v = 0.f;
    if (k < kH)               v = W_hh[g * kH + k];
    else if (k < kH + kD)     v = W_ih[g * kD + (k - kH)];
    Wt[idx] = (__bf16)v;   // idx == p*kKPad + k
  }
  if (tid < kG) {
    int u = tid >> 2, q = tid & 3, g = q * kH + u;
    biasp[tid] = b_ih[g] + b_hh[g];
  }
  if (tid >= kG && tid < kG + 16) {
    int t = tid - kG;
    wxp[t] = (t < kT) ? W_attn[2 * kH + t] : 0.f;
  }
  if (tid == kG + 16) bap[0] = b_attn[0];
}

__global__ __launch_bounds__(kTh, 2) void enc_main(
    const float* __restrict__ x,              // (B,9,81) fp32
    const unsigned char* __restrict__ ws,
    float* __restrict__ out_w,                // (B,9,81) fp32
    float* __restrict__ out_h) {              // (B,9,128) fp32
  // Activations^T stored as [b][k] row-major bf16, hi and lo planes.
  // k<128: h, 128..208: w_in, 209..231: zero pad.
  __shared__ __align__(16) __bf16 ash[kNB][kAS];
  __shared__ __align__(16) __bf16 asl[kNB][kAS];
  __shared__ __align__(16) float bias_s[kG];
  __shared__ float red[kNB][8];
  __shared__ float wx_s[16];
  __shared__ float battn_s;

  const int tid = threadIdx.x;
  const int b0  = blockIdx.x * kNB;
  const __bf16* Wt = reinterpret_cast<const __bf16*>(ws);

  if (tid < 16) wx_s[tid] = reinterpret_cast<const float*>(ws + kWsWxOff)[tid];
  if (tid == 16) battn_s = reinterpret_cast<const float*>(ws + kWsBAttnOff)[0];
  bias_s[tid]       = reinterpret_cast<const float*>(ws + kWsBiasOff)[tid];
  bias_s[tid + 256] = reinterpret_cast<const float*>(ws + kWsBiasOff)[tid + 256];
  for (int i = tid; i < kNB * kAS; i += kTh) {   // zero (h0=0, k-pad=0)
    (&ash[0][0])[i] = (__bf16)0.f;
    (&asl[0][0])[i] = (__bf16)0.f;
  }
  __syncthreads();

  // ---- pre + softmax once (time-invariant). thread: b = tid>>3, d = (tid&7)+8m
  const int sb = tid >> 3;
  const int sq = tid & 7;
  const size_t xbase = (size_t)(b0 + sb) * kT * kD;
  float attn[11];
  {
    float lmax = -3.4e38f;
#pragma unroll
    for (int m = 0; m < 11; ++m) {
      int d = sq + 8 * m;
      float s = -3.4e38f;
      if (d < kD) {
        s = battn_s;
#pragma unroll
        for (int t = 0; t < kT; ++t)
          s += x[xbase + t * kD + d] * wx_s[t];
        lmax = fmaxf(lmax, s);
      }
      attn[m] = s;
    }
    red[sb][sq] = lmax;
    __syncthreads();
    float gmax = red[sb][0];
#pragma unroll
    for (int r = 1; r < 8; ++r) gmax = fmaxf(gmax, red[sb][r]);
    __syncthreads();
    float lsum = 0.f;
#pragma unroll
    for (int m = 0; m < 11; ++m) {
      float e = __expf(attn[m] - gmax);   // invalid lanes: exp(-huge) = 0
      attn[m] = e;
      lsum += e;
    }
    red[sb][sq] = lsum;
    __syncthreads();
    float tot = 0.f;
#pragma unroll
    for (int r = 0; r < 8; ++r) tot += red[sb][r];
    float inv = 1.0f / tot;
#pragma unroll
    for (int m = 0; m < 11; ++m) attn[m] *= inv;
  }

  // ---- MFMA ids: wave wv owns gate-rows [wv*128,(wv+1)*128) (8 p-tiles),
  //      32 batches (2 batch-tiles of 16).
  const int lane = tid & 63;
  const int wv   = tid >> 6;
  const int lb   = lane & 15;   // A row within p-tile / B col (batch) / D col
  const int kg   = lane >> 4;   // k-group: k = ks*32 + kg*8 + j
  const __bf16* wrow = Wt + (size_t)(wv * 128 + lb) * kKPad;

  float c_reg[2][8];
#pragma unroll
  for (int bt = 0; bt < 2; ++bt)
#pragma unroll
    for (int p = 0; p < 8; ++p) c_reg[bt][p] = 0.f;

  // prologue: prefetch x_0 into registers (plain cached loads)
  float xr[11];
#pragma unroll
  for (int m = 0; m < 11; ++m) {
    int d = sq + 8 * m;
    xr[m] = (d < kD) ? x[xbase + d] : 0.f;
  }

  for (int t = 0; t < kT; ++t) {
    // ---- phase A: w_in = attn * x_t (prefetched) -> hi/lo planes at
    //      k=128+d + out_w NT (full 64B segments); prefetch x_{t+1}.
    {
      const size_t xoff = xbase + (size_t)t * kD;
#pragma unroll
      for (int m = 0; m < 11; ++m) {
        int d = sq + 8 * m;
        if (d < kD) {
          float w = attn[m] * xr[m];
          __builtin_nontemporal_store(w, out_w + xoff + d);
          __bf16 hi = (__bf16)w;
          ash[sb][kH + d] = hi;
          asl[sb][kH + d] = (__bf16)(w - (float)hi);
        }
      }
      if (t + 1 < kT) {
#pragma unroll
        for (int m = 0; m < 11; ++m) {
          int d = sq + 8 * m;
          if (d < kD) xr[m] = x[xoff + kD + d];
        }
      }
    }
    __syncthreads();   // w_in writes (t) + h writes (t-1) visible to all waves

    // ---- gates = act @ W^T via MFMA, acc init = bias quad
    f32x4 acc[2][8];
#pragma unroll
    for (int p = 0; p < 8; ++p) {
      f32x4 bv = *reinterpret_cast<const f32x4*>(
          &bias_s[wv * 128 + p * 16 + kg * 4]);
      acc[0][p] = bv;
      acc[1][p] = bv;
    }
#pragma unroll
    for (int ks = 0; ks < kKPad / 32; ++ks) {
      const int k0 = ks * 32 + kg * 8;
      bf16x8 wf[8];
#pragma unroll
      for (int p = 0; p < 8; ++p)
        wf[p] = *reinterpret_cast<const bf16x8*>(wrow + p * (16 * kKPad) + k0);
#pragma unroll
      for (int bt = 0; bt < 2; ++bt) {
        bf16x8 bh = *reinterpret_cast<const bf16x8*>(&ash[bt * 16 + lb][k0]);
        bf16x8 bl = *reinterpret_cast<const bf16x8*>(&asl[bt * 16 + lb][k0]);
#pragma unroll
        for (int p = 0; p < 8; ++p) {
          acc[bt][p] = __builtin_amdgcn_mfma_f32_16x16x32_bf16(wf[p], bh, acc[bt][p], 0, 0, 0);
          acc[bt][p] = __builtin_amdgcn_mfma_f32_16x16x32_bf16(wf[p], bl, acc[bt][p], 0, 0, 0);
        }
      }
    }
    __syncthreads();   // all waves' GEMM reads done before h-region rewrite

    // ---- LSTM pointwise: lane holds {i,f,g,o} (= reg 0..3) of (b,u)
    //      b = bt*16 + lb, u = wv*32 + p*4 + kg; c stays in registers.
    //      h goes to LDS only (hi/lo); global store happens staged below.
#pragma unroll
    for (int p = 0; p < 8; ++p) {
      const int u = wv * 32 + p * 4 + kg;
#pragma unroll
      for (int bt = 0; bt < 2; ++bt) {
        f32x4 g4 = acc[bt][p];
        float cn = sigf(g4[1]) * c_reg[bt][p] + sigf(g4[0]) * tanhfast(g4[2]);
        float hn = sigf(g4[3]) * tanhfast(cn);
        c_reg[bt][p] = cn;
        const int b = bt * 16 + lb;
        __bf16 hi = (__bf16)hn;
        ash[b][u] = hi;                             // h region at k = u
        asl[b][u] = (__bf16)(hn - (float)hi);
      }
    }
    __syncthreads();   // h hi/lo visible to staging threads

    // ---- staged coalesced out_h store: h = hi + lo (err ~4e-6).
    //      thread: b = tid>>3, u0 = (tid&7)*16; 512B contiguous per row.
    {
      const int hb = tid >> 3;
      const int u0 = (tid & 7) * 16;
      float* orow = out_h + ((size_t)(b0 + hb) * kT + t) * kH + u0;
      bf16x8 h0 = *reinterpret_cast<const bf16x8*>(&ash[hb][u0]);
      bf16x8 h1 = *reinterpret_cast<const bf16x8*>(&ash[hb][u0 + 8]);
      bf16x8 l0 = *reinterpret_cast<const bf16x8*>(&asl[hb][u0]);
      bf16x8 l1 = *reinterpret_cast<const bf16x8*>(&asl[hb][u0 + 8]);
      f32x4 v;
#pragma unroll
      for (int i = 0; i < 4; ++i) v[i] = (float)h0[i] + (float)l0[i];
      __builtin_nontemporal_store(v, reinterpret_cast<f32x4*>(orow));
#pragma unroll
      for (int i = 0; i < 4; ++i) v[i] = (float)h0[4 + i] + (float)l0[4 + i];
      __builtin_nontemporal_store(v, reinterpret_cast<f32x4*>(orow + 4));
#pragma unroll
      for (int i = 0; i < 4; ++i) v[i] = (float)h1[i] + (float)l1[i];
      __builtin_nontemporal_store(v, reinterpret_cast<f32x4*>(orow + 8));
#pragma unroll
      for (int i = 0; i < 4; ++i) v[i] = (float)h1[4 + i] + (float)l1[4 + i];
      __builtin_nontemporal_store(v, reinterpret_cast<f32x4*>(orow + 12));
    }
    // no barrier here: next phase A writes w_in region (disjoint from h);
    // next GEMM reads are ordered by the post-phase-A barrier; next
    // pointwise h-rewrite is ordered by the post-GEMM barrier.
  }
}

}  // namespace

extern "C" void kernel_launch(void* const* d_in, const int* in_sizes, int n_in,
                              void* d_out, int out_size, void* d_ws, size_t ws_size,
                              hipStream_t stream) {
  (void)in_sizes; (void)n_in; (void)out_size; (void)ws_size;
  const float* x      = (const float*)d_in[0];
  const float* W_attn = (const float*)d_in[1];
  const float* b_attn = (const float*)d_in[2];
  const float* W_ih   = (const float*)d_in[3];
  const float* W_hh   = (const float*)d_in[4];
  const float* b_ih   = (const float*)d_in[5];
  const float* b_hh   = (const float*)d_in[6];
  float* out_w = (float*)d_out;
  float* out_h = out_w + (size_t)kB * kT * kD;
  unsigned char* ws = (unsigned char*)d_ws;

  hipLaunchKernelGGL(prep_kernel, dim3(64), dim3(256), 0, stream,
                     W_attn, b_attn, W_ih, W_hh, b_ih, b_hh, ws);
  hipLaunchKernelGGL(enc_main, dim3(kB / kNB), dim3(kTh), 0, stream,
                     x, ws, out_w, out_h);
}

// Round 8
// 620.680 us; speedup vs baseline: 1.9305x; 1.6186x over previous
//
#include <hip/hip_runtime.h>
#include <hip/hip_bf16.h>

// Encoder: attention-weighted LSTM, B=32768 T=9 D_IN=81 H=128.
// All inputs AND outputs fp32. attn = softmax(pre) is time-invariant
// (logits = pre + scalar broadcast); Wh/Wc dead. Recurrence:
// gates_t = [w_in_t | h_t] @ [W_ih | W_hh]^T + bias.
//
// History:
//  r1: MFMA rewrite 403us. FETCH 664MB (W refetch ~470, mostly L3-served),
//      WRITE 373MB, occ 22% -- latency-bound.
//  r3/r4: occupancy chase regressed (~940us): gfx950 unified VGPR/AGPR
//      budget (512/waves) caused spills at bounds(512,4); NT partial-line
//      stores amplified writes.
//  r5: staged out_h, 782us but WRITE 1.71GB / FETCH 1.18GB: quarter-line NT
//      stores (16B/lane at 64B stride) => ~4x write amplification + RMW
//      fetches. LESSON: NT only when each 8-lane cluster covers full 64B
//      lines; else plain stores (L2 write-allocate merges).
//  r6/r7: 3-kernel split (enc_main re-reading d_out) -- container failed
//      twice, twice. No bug found on audit; structure abandoned anyway.
//  r8 (this): r5's proven single-fused-kernel shape + store fixes only:
//      - out_w: PLAIN stores (r1-proven; L2 merges 32B clusters, WRITE
//        was 282MB).
//      - out_h: staged via LDS, NT stores with FULL-LINE mapping: thread
//        (row sb=tid>>3, seg sq=tid&7), store j at float offset sq*4+j*32
//        => per instruction 8-lane clusters cover 128B contiguous.
//      - 2 barriers/t (was 3): w_in(t+1) compute + out_w store moved into
//        the GEMM-drain window; LDS staging after barB.
//      - xr(0) captured during softmax pass (one fewer x read).
// MFMA layout (HW-verified C/D: col=lane&15=batch, row=(lane>>4)*4+reg=p):
// A = W^T tile (M=gate-row p), B = activations^T (N=batch); both operands
// contiguous-8-along-k so internal k-permutation cancels. Gate-row perm
// p=4u+q => lane's f32x4 acc = {i,f,g,o} of one (b,u): pointwise lane-local.
// fp32 activation accuracy via bf16 hi+lo planes (2 MFMAs per W fragment).

namespace {

constexpr int kB    = 32768;
constexpr int kT    = 9;
constexpr int kD    = 81;     // D_IN
constexpr int kH    = 128;
constexpr int kG    = 512;    // 4H
constexpr int kKPad = 224;    // 7 MFMA k-steps of 32; k<128: h, 128..208: w_in,
                              // 209..223: zero pad
constexpr int kNB   = 32;     // batch rows per block
constexpr int kTh   = 256;    // threads per block (4 waves)
constexpr int kAS   = 232;    // LDS activation row stride in bf16 (464B = 29*16:
                              // rows 16B-aligned; dword stride 116 == 20 mod 32
                              // -> 2-way bank alias, free)

// ws layout: [Wt bf16 [512][224] gate-permuted rows][bias 512 f32][Wx 16 f32][b_attn f32]
constexpr int kWsWtBytes  = kG * kKPad * 2;      // 229376
constexpr int kWsBiasOff  = kWsWtBytes;
constexpr int kWsWxOff    = kWsBiasOff + kG * 4;
constexpr int kWsBAttnOff = kWsWxOff + 16 * 4;

typedef __bf16 bf16x8 __attribute__((ext_vector_type(8)));
typedef __bf16 bf16x4 __attribute__((ext_vector_type(4)));
typedef float  f32x4  __attribute__((ext_vector_type(4)));

__device__ __forceinline__ float sigf(float x) {
  return __builtin_amdgcn_rcpf(1.f + __expf(-x));
}
// tanh(x) = 1 - 2/(1+e^{2x}); saturates correctly as exp -> 0/inf
__device__ __forceinline__ float tanhfast(float x) {
  return 1.f - 2.f * __builtin_amdgcn_rcpf(1.f + __expf(2.f * x));
}

// ---- prep: repack weights. Gate-row perm p = u*4+q (gate g = q*128+u).
// W stored TRANSPOSED [p][k] bf16, k-layout matching LDS activations:
// k<128 -> W_hh[g][k]; 128<=k<209 -> W_ih[g][k-128]; else 0.
__global__ void prep_kernel(const float* __restrict__ W_attn,
                            const float* __restrict__ b_attn,
                            const float* __restrict__ W_ih,
                            const float* __restrict__ W_hh,
                            const float* __restrict__ b_ih,
                            const float* __restrict__ b_hh,
                            unsigned char* __restrict__ ws) {
  __bf16* Wt   = reinterpret_cast<__bf16*>(ws);
  float* biasp = reinterpret_cast<float*>(ws + kWsBiasOff);
  float* wxp   = reinterpret_cast<float*>(ws + kWsWxOff);
  float* bap   = reinterpret_cast<float*>(ws + kWsBAttnOff);
  int tid = blockIdx.x * blockDim.x + threadIdx.x;
  int nth = gridDim.x * blockDim.x;
  for (int idx = tid; idx < kG * kKPad; idx += nth) {
    int p = idx / kKPad, k = idx - p * kKPad;
    int u = p >> 2, q = p & 3, g = q * kH + u;
    float v = 0.f;
    if (k < kH)           v = W_hh[g * kH + k];
    else if (k < kH + kD) v = W_ih[g * kD + (k - kH)];
    Wt[idx] = (__bf16)v;   // idx == p*kKPad + k
  }
  if (tid < kG) {
    int u = tid >> 2, q = tid & 3, g = q * kH + u;
    biasp[tid] = b_ih[g] + b_hh[g];
  }
  if (tid >= kG && tid < kG + 16) {
    int t = tid - kG;
    wxp[t] = (t < kT) ? W_attn[2 * kH + t] : 0.f;
  }
  if (tid == kG + 16) bap[0] = b_attn[0];
}

__global__ __launch_bounds__(kTh, 2) void enc_main(
    const float* __restrict__ x,              // (B,9,81) fp32
    const unsigned char* __restrict__ ws,
    float* __restrict__ out_w,                // (B,9,81) fp32
    float* __restrict__ out_h) {              // (B,9,128) fp32
  // Activations^T [b][k] bf16 hi/lo planes. k<128: h, 128..208: w_in, pad 0.
  __shared__ __align__(16) __bf16 ash[kNB][kAS];
  __shared__ __align__(16) __bf16 asl[kNB][kAS];
  __shared__ __align__(16) float bias_s[kG];
  __shared__ float red[kNB][8];
  __shared__ float wx_s[16];
  __shared__ float battn_s;

  const int tid = threadIdx.x;
  const int b0  = blockIdx.x * kNB;
  const __bf16* Wt = reinterpret_cast<const __bf16*>(ws);

  if (tid < 16) wx_s[tid] = reinterpret_cast<const float*>(ws + kWsWxOff)[tid];
  if (tid == 16) battn_s = reinterpret_cast<const float*>(ws + kWsBAttnOff)[0];
  bias_s[tid]       = reinterpret_cast<const float*>(ws + kWsBiasOff)[tid];
  bias_s[tid + 256] = reinterpret_cast<const float*>(ws + kWsBiasOff)[tid + 256];
  for (int i = tid; i < kNB * kAS; i += kTh) {   // zero (h0=0, k-pads=0)
    (&ash[0][0])[i] = (__bf16)0.f;
    (&asl[0][0])[i] = (__bf16)0.f;
  }
  __syncthreads();

  // ---- pre + softmax (time-invariant). thread: b = tid>>3, d = (tid&7)+8m.
  // Captures x(t=0) into xr during the pass.
  const int sb = tid >> 3;
  const int sq = tid & 7;
  const size_t xbase = (size_t)(b0 + sb) * kT * kD;
  float attn[11];
  float xr[11];
  {
    float lmax = -3.4e38f;
#pragma unroll
    for (int m = 0; m < 11; ++m) {
      int d = sq + 8 * m;
      float s = -3.4e38f;
      xr[m] = 0.f;
      if (d < kD) {
        s = battn_s;
#pragma unroll
        for (int t = 0; t < kT; ++t) {
          float xv = x[xbase + t * kD + d];
          if (t == 0) xr[m] = xv;
          s += xv * wx_s[t];
        }
        lmax = fmaxf(lmax, s);
      }
      attn[m] = s;
    }
    red[sb][sq] = lmax;
    __syncthreads();
    float gmax = red[sb][0];
#pragma unroll
    for (int r = 1; r < 8; ++r) gmax = fmaxf(gmax, red[sb][r]);
    __syncthreads();
    float lsum = 0.f;
#pragma unroll
    for (int m = 0; m < 11; ++m) {
      float e = __expf(attn[m] - gmax);   // invalid lanes: exp(-huge) = 0
      attn[m] = e;
      lsum += e;
    }
    red[sb][sq] = lsum;
    __syncthreads();
    float tot = 0.f;
#pragma unroll
    for (int r = 0; r < 8; ++r) tot += red[sb][r];
    float inv = 1.0f / tot;
#pragma unroll
    for (int m = 0; m < 11; ++m) attn[m] *= inv;
  }

  // ---- prologue: w_in(0) = attn * x(0): store out_w (plain) + LDS hi/lo.
  // (Softmax barriers above order this after the zero-init.)
#pragma unroll
  for (int m = 0; m < 11; ++m) {
    int d = sq + 8 * m;
    if (d < kD) {
      float w = attn[m] * xr[m];
      out_w[xbase + d] = w;
      __bf16 hi = (__bf16)w;
      ash[sb][kH + d] = hi;
      asl[sb][kH + d] = (__bf16)(w - (float)hi);
    }
  }

  // MFMA ids: wave wv owns gate-rows [wv*128,(wv+1)*128), 32 batches.
  const int lane = tid & 63;
  const int wv   = tid >> 6;
  const int lb   = lane & 15;
  const int kg   = lane >> 4;
  const __bf16* wrow = Wt + (size_t)(wv * 128 + lb) * kKPad;

  float c_reg[2][8];
#pragma unroll
  for (int bt = 0; bt < 2; ++bt)
#pragma unroll
    for (int p = 0; p < 8; ++p) c_reg[bt][p] = 0.f;

  __syncthreads();   // w_in(0) visible to all waves

  for (int t = 0; t < kT; ++t) {
    // ---- issue x(t+1) loads early: vmem latency overlaps the MFMA block
    if (t + 1 < kT) {
      const size_t xoff1 = xbase + (size_t)(t + 1) * kD;
#pragma unroll
      for (int m = 0; m < 11; ++m) {
        int d = sq + 8 * m;
        if (d < kD) xr[m] = x[xoff1 + d];
      }
    }

    // ---- gates = act @ W^T via MFMA, acc init = bias quad
    f32x4 acc[2][8];
#pragma unroll
    for (int p = 0; p < 8; ++p) {
      f32x4 bv = *reinterpret_cast<const f32x4*>(
          &bias_s[wv * 128 + p * 16 + kg * 4]);
      acc[0][p] = bv;
      acc[1][p] = bv;
    }
#pragma unroll
    for (int ks = 0; ks < kKPad / 32; ++ks) {
      const int k0 = ks * 32 + kg * 8;
      bf16x8 wf[8];
#pragma unroll
      for (int p = 0; p < 8; ++p)
        wf[p] = *reinterpret_cast<const bf16x8*>(wrow + p * (16 * kKPad) + k0);
#pragma unroll
      for (int bt = 0; bt < 2; ++bt) {
        bf16x8 bh = *reinterpret_cast<const bf16x8*>(&ash[bt * 16 + lb][k0]);
        bf16x8 bl = *reinterpret_cast<const bf16x8*>(&asl[bt * 16 + lb][k0]);
#pragma unroll
        for (int p = 0; p < 8; ++p) {
          acc[bt][p] = __builtin_amdgcn_mfma_f32_16x16x32_bf16(wf[p], bh, acc[bt][p], 0, 0, 0);
          acc[bt][p] = __builtin_amdgcn_mfma_f32_16x16x32_bf16(wf[p], bl, acc[bt][p], 0, 0, 0);
        }
      }
    }

    // ---- w_in(t+1) = attn * x(t+1): out_w store (PLAIN: L2 merges the
    // 32B clusters; r5's NT here caused RMW+amplification). Keep w in xr
    // for the LDS staging after barB.
    if (t + 1 < kT) {
      const size_t xoff1 = xbase + (size_t)(t + 1) * kD;
#pragma unroll
      for (int m = 0; m < 11; ++m) {
        int d = sq + 8 * m;
        if (d < kD) {
          float w = attn[m] * xr[m];
          out_w[xoff1 + d] = w;
          xr[m] = w;
        }
      }
    }
    __syncthreads();   // barB: all GEMM LDS reads done before rewrites

    // ---- LSTM pointwise: lane holds {i,f,g,o} of (b = bt*16+lb, u).
#pragma unroll
    for (int p = 0; p < 8; ++p) {
      const int u = wv * 32 + p * 4 + kg;
#pragma unroll
      for (int bt = 0; bt < 2; ++bt) {
        f32x4 g4 = acc[bt][p];
        float cn = sigf(g4[1]) * c_reg[bt][p] + sigf(g4[0]) * tanhfast(g4[2]);
        float hn = sigf(g4[3]) * tanhfast(cn);
        c_reg[bt][p] = cn;
        const int b = bt * 16 + lb;
        __bf16 hi = (__bf16)hn;
        ash[b][u] = hi;                             // h region, k = u
        asl[b][u] = (__bf16)(hn - (float)hi);
      }
    }
    // ---- stage w_in(t+1) into LDS (region already read by GEMM(t))
    if (t + 1 < kT) {
#pragma unroll
      for (int m = 0; m < 11; ++m) {
        int d = sq + 8 * m;
        if (d < kD) {
          float w = xr[m];
          __bf16 hi = (__bf16)w;
          ash[sb][kH + d] = hi;
          asl[sb][kH + d] = (__bf16)(w - (float)hi);
        }
      }
    }
    __syncthreads();   // barC: h(t) + w_in(t+1) visible

    // ---- out_h(t) store, FULL-LINE NT: thread (row sb, seg sq); store j at
    // float offset sq*4 + j*32 => per instruction the 8 lanes of each
    // sb-cluster cover 128B contiguous (2 full 64B lines, 128B-aligned:
    // row base (b*9+t)*512B). h = hi+lo (err ~4e-6 << 4.9e-4 margin).
    {
      float* orow = out_h + ((size_t)(b0 + sb) * kT + t) * kH;
#pragma unroll
      for (int j = 0; j < 4; ++j) {
        const int o = sq * 4 + j * 32;
        bf16x4 h4 = *reinterpret_cast<const bf16x4*>(&ash[sb][o]);
        bf16x4 l4 = *reinterpret_cast<const bf16x4*>(&asl[sb][o]);
        f32x4 v;
#pragma unroll
        for (int i = 0; i < 4; ++i) v[i] = (float)h4[i] + (float)l4[i];
        __builtin_nontemporal_store(v, reinterpret_cast<f32x4*>(orow + o));
      }
    }
    // no barrier: this store phase and the next GEMM both only READ LDS;
    // next writes (h, w_in) are after next barB.
  }
}

}  // namespace

extern "C" void kernel_launch(void* const* d_in, const int* in_sizes, int n_in,
                              void* d_out, int out_size, void* d_ws, size_t ws_size,
                              hipStream_t stream) {
  (void)in_sizes; (void)n_in; (void)out_size; (void)ws_size;
  const float* x      = (const float*)d_in[0];
  const float* W_attn = (const float*)d_in[1];
  const float* b_attn = (const float*)d_in[2];
  const float* W_ih   = (const float*)d_in[3];
  const float* W_hh   = (const float*)d_in[4];
  const float* b_ih   = (const float*)d_in[5];
  const float* b_hh   = (const float*)d_in[6];
  float* out_w = (float*)d_out;
  float* out_h = out_w + (size_t)kB * kT * kD;
  unsigned char* ws = (unsigned char*)d_ws;

  hipLaunchKernelGGL(prep_kernel, dim3(64), dim3(256), 0, stream,
                     W_attn, b_attn, W_ih, W_hh, b_ih, b_hh, ws);
  hipLaunchKernelGGL(enc_main, dim3(kB / kNB), dim3(kTh), 0, stream,
                     x, ws, out_w, out_h);
}